// Round 1
// baseline (725.185 us; speedup 1.0000x reference)
//
#include <hip/hip_runtime.h>
#include <math.h>

typedef __attribute__((ext_vector_type(8))) short short8;
typedef __attribute__((ext_vector_type(4))) float f32x4;

#define B_ 16
#define T_ 256
#define I_ 64
#define H_ 128
#define K_ 64
#define U_ 256
#define KC 16
#define NTHR 512

#define OUT_OFF_P (B_*T_*H_)              /* 524288 */
#define OUT_OFF_LW (OUT_OFF_P + B_*K_*H_) /* 655360 */

__device__ __forceinline__ unsigned short f2bf(float x) {
    unsigned int u = __float_as_uint(x);
    u += 0x7fffu + ((u >> 16) & 1u);   // round-to-nearest-even (finite inputs)
    return (unsigned short)(u >> 16);
}
__device__ __forceinline__ float fast_tanh(float x) {
    float e = __expf(2.0f * x);
    return 1.0f - 2.0f * __builtin_amdgcn_rcpf(e + 1.0f);
}
__device__ __forceinline__ float fast_sigmoid(float x) {
    return __builtin_amdgcn_rcpf(1.0f + __expf(-x));
}
// XOR-swizzled LDS addressing (returns ushort index); both write & read sides use it.
__device__ __forceinline__ unsigned int swz_p(unsigned int row, unsigned int col) { // [16][128] bf16
    unsigned int byte = row * 256u + col * 2u;
    byte ^= (row & 7u) << 4;
    return byte >> 1;
}
__device__ __forceinline__ unsigned int swz_b(unsigned int row, unsigned int col) { // [16][256] bf16
    unsigned int byte = row * 512u + col * 2u;
    byte ^= (row & 7u) << 4;
    return byte >> 1;
}

__global__ __launch_bounds__(NTHR, 2) void pf_kernel(
    const float* __restrict__ x, const float* __restrict__ tspan,
    const float* __restrict__ eps, const float* __restrict__ Wb,
    const float* __restrict__ bb,
    const float* __restrict__ Wf1, const float* __restrict__ bf1,
    const float* __restrict__ Wf2, const float* __restrict__ bf2,
    const float* __restrict__ Wta, const float* __restrict__ bta,
    const float* __restrict__ Wtb, const float* __restrict__ btb,
    const float* __restrict__ nscale, float* __restrict__ out)
{
    const int tid  = threadIdx.x;
    const int lane = tid & 63;
    const int wv   = tid >> 6;        // wave 0..7
    const int ln15 = lane & 15;
    const int l4   = lane >> 4;
    const int bid  = blockIdx.x;      // 0..63
    const int b    = bid >> 2;
    const int k0   = (bid & 3) * KC;

    __shared__ unsigned short p_bf[KC * H_];     // particles, bf16, swizzled
    __shared__ unsigned short bbk_bf[KC * U_];   // backbone acts, bf16, swizzled
    __shared__ float heads[4][KC][H_ + 4];       // ff1/ff2/ta/tb, padded
    __shared__ float red[4][H_];                 // partial-mean reduce

    for (int i = tid; i < KC * H_; i += NTHR) p_bf[i] = 0;

    // ---- persistent weight fragments (bf16, registers) ----
    // GEMM1: Wb (192x256). wave wv owns cols [wv*32, wv*32+32). B-frag lane map:
    // n = lane&15, k = (lane>>4)*8 + j  (16x16x32 bf16).
    short8 B1[6][2];
    #pragma unroll
    for (int kt = 0; kt < 6; ++kt) {
        #pragma unroll
        for (int ct = 0; ct < 2; ++ct) {
            short8 f;
            const int col = wv * 32 + ct * 16 + ln15;
            #pragma unroll
            for (int j = 0; j < 8; ++j) {
                const int k = kt * 32 + l4 * 8 + j;
                f[j] = (short)f2bf(Wb[k * U_ + col]);
            }
            B1[kt][ct] = f;
        }
    }
    // GEMM2: 512-col space = [ff1|ff2|ta|tb]; wave wv owns cols [wv*64, wv*64+64).
    const float* Wh = (wv < 2) ? Wf1 : (wv < 4) ? Wf2 : (wv < 6) ? Wta : Wtb;
    const float* bh = (wv < 2) ? bf1 : (wv < 4) ? bf2 : (wv < 6) ? bta : btb;
    const int hcol0 = (wv & 1) * 64;
    short8 B2[8][4];
    #pragma unroll
    for (int kt = 0; kt < 8; ++kt) {
        #pragma unroll
        for (int ct = 0; ct < 4; ++ct) {
            short8 f;
            const int h = hcol0 + ct * 16 + ln15;
            #pragma unroll
            for (int j = 0; j < 8; ++j) {
                const int k = kt * 32 + l4 * 8 + j;
                f[j] = (short)f2bf(Wh[k * H_ + h]);
            }
            B2[kt][ct] = f;
        }
    }
    float bias1[2];
    #pragma unroll
    for (int ct = 0; ct < 2; ++ct) bias1[ct] = bb[wv * 32 + ct * 16 + ln15];
    float bias2[4];
    #pragma unroll
    for (int ct = 0; ct < 4; ++ct) bias2[ct] = bh[hcol0 + ct * 16 + ln15];

    const int g  = tid >> 7;          // 0..3 (row group for combine)
    const int hh = tid & (H_ - 1);    // h for combine
    const float nsc = nscale[hh];
    const int hd = wv >> 1;
    const bool isff = (wv < 4);

    if ((bid & 3) == 0 && tid < K_)
        out[OUT_OFF_LW + b * K_ + tid] = -4.1588830833596715f; // -log(64)

    __syncthreads();

    const f32x4 zero4 = {0.f, 0.f, 0.f, 0.f};

    for (int t = 0; t < T_; ++t) {
        // prefetch step inputs early; consumed at combine
        const float ts = tspan[b * T_ + t];
        const float sq = sqrtf(ts);
        float epsv[4];
        #pragma unroll
        for (int i = 0; i < 4; ++i)
            epsv[i] = eps[(size_t)((t * B_ + b) * K_ + k0 + g * 4 + i) * H_ + hh];

        // x part of z as register A-fragments (identical across all 16 rows)
        short8 ax[2];
        #pragma unroll
        for (int kt = 0; kt < 2; ++kt) {
            const float* xp = &x[(b * T_ + t) * I_ + kt * 32 + l4 * 8];
            short8 f;
            #pragma unroll
            for (int j = 0; j < 8; ++j) f[j] = (short)f2bf(xp[j]);
            ax[kt] = f;
        }

        // ---- GEMM1: z(16x192) @ Wb -> bbk(16x256) ----
        f32x4 acc10 = zero4, acc11 = zero4;
        #pragma unroll
        for (int kt = 0; kt < 2; ++kt) {
            acc10 = __builtin_amdgcn_mfma_f32_16x16x32_bf16(ax[kt], B1[kt][0], acc10, 0, 0, 0);
            acc11 = __builtin_amdgcn_mfma_f32_16x16x32_bf16(ax[kt], B1[kt][1], acc11, 0, 0, 0);
        }
        #pragma unroll
        for (int kt = 0; kt < 4; ++kt) {
            const short8 a = *(const short8*)&p_bf[swz_p(ln15, kt * 32 + l4 * 8)];
            acc10 = __builtin_amdgcn_mfma_f32_16x16x32_bf16(a, B1[2 + kt][0], acc10, 0, 0, 0);
            acc11 = __builtin_amdgcn_mfma_f32_16x16x32_bf16(a, B1[2 + kt][1], acc11, 0, 0, 0);
        }
        #pragma unroll
        for (int r = 0; r < 4; ++r) {                 // C: row=(l>>4)*4+r, col=l&15
            const int row = l4 * 4 + r;
            const float v0 = 1.7159f * fast_tanh(0.666f * (acc10[r] + bias1[0]));
            const float v1 = 1.7159f * fast_tanh(0.666f * (acc11[r] + bias1[1]));
            bbk_bf[swz_b(row, wv * 32 + ln15)]      = f2bf(v0);
            bbk_bf[swz_b(row, wv * 32 + 16 + ln15)] = f2bf(v1);
        }
        __syncthreads();

        // ---- GEMM2: bbk(16x256) @ [Wf1|Wf2|Wta|Wtb](256x512) ----
        f32x4 acc20 = zero4, acc21 = zero4, acc22 = zero4, acc23 = zero4;
        #pragma unroll
        for (int kt = 0; kt < 8; ++kt) {
            const short8 a = *(const short8*)&bbk_bf[swz_b(ln15, kt * 32 + l4 * 8)];
            acc20 = __builtin_amdgcn_mfma_f32_16x16x32_bf16(a, B2[kt][0], acc20, 0, 0, 0);
            acc21 = __builtin_amdgcn_mfma_f32_16x16x32_bf16(a, B2[kt][1], acc21, 0, 0, 0);
            acc22 = __builtin_amdgcn_mfma_f32_16x16x32_bf16(a, B2[kt][2], acc22, 0, 0, 0);
            acc23 = __builtin_amdgcn_mfma_f32_16x16x32_bf16(a, B2[kt][3], acc23, 0, 0, 0);
        }
        #pragma unroll
        for (int r = 0; r < 4; ++r) {
            const int row = l4 * 4 + r;
            float v0 = acc20[r] + bias2[0];
            float v1 = acc21[r] + bias2[1];
            float v2 = acc22[r] + bias2[2];
            float v3 = acc23[r] + bias2[3];
            if (isff) { v0 = fast_tanh(v0); v1 = fast_tanh(v1); v2 = fast_tanh(v2); v3 = fast_tanh(v3); }
            heads[hd][row][hcol0 + ln15]      = v0;
            heads[hd][row][hcol0 + 16 + ln15] = v1;
            heads[hd][row][hcol0 + 32 + ln15] = v2;
            heads[hd][row][hcol0 + 48 + ln15] = v3;
        }
        __syncthreads();

        // ---- combine: interp + noise; update particles; partial mean ----
        float psum = 0.f;
        #pragma unroll
        for (int i = 0; i < 4; ++i) {
            const int r = g * 4 + i;
            const float f1v = heads[0][r][hh];
            const float f2v = heads[1][r][hh];
            const float tav = heads[2][r][hh];
            const float tbv = heads[3][r][hh];
            const float tiv = fast_sigmoid(tav * ts + tbv);
            const float np  = f1v + tiv * (f2v - f1v) + nsc * sq * epsv[i];
            p_bf[swz_p(r, hh)] = f2bf(np);
            psum += np;
            if (t == T_ - 1) out[OUT_OFF_P + (b * K_ + k0 + r) * H_ + hh] = np;
        }
        red[g][hh] = psum;
        __syncthreads();
        if (tid < H_) {
            const float s = (red[0][hh] + red[1][hh] + red[2][hh] + red[3][hh]) * (1.0f / 64.0f);
            atomicAdd(&out[(b * T_ + t) * H_ + hh], s);
        }
    }
}

extern "C" void kernel_launch(void* const* d_in, const int* in_sizes, int n_in,
                              void* d_out, int out_size, void* d_ws, size_t ws_size,
                              hipStream_t stream) {
    const float* x    = (const float*)d_in[0];
    const float* tsp  = (const float*)d_in[1];
    const float* eps  = (const float*)d_in[2];
    const float* Wb   = (const float*)d_in[3];
    const float* bb   = (const float*)d_in[4];
    const float* Wf1  = (const float*)d_in[5];
    const float* bf1  = (const float*)d_in[6];
    const float* Wf2  = (const float*)d_in[7];
    const float* bf2  = (const float*)d_in[8];
    const float* Wta  = (const float*)d_in[9];
    const float* bta  = (const float*)d_in[10];
    const float* Wtb  = (const float*)d_in[11];
    const float* btb  = (const float*)d_in[12];
    const float* nsc  = (const float*)d_in[13];
    float* out = (float*)d_out;

    // outputs region is accumulated with atomics -> must be zeroed every launch
    (void)hipMemsetAsync(d_out, 0, (size_t)OUT_OFF_P * sizeof(float), stream);
    pf_kernel<<<dim3(64), dim3(NTHR), 0, stream>>>(
        x, tsp, eps, Wb, bb, Wf1, bf1, Wf2, bf2, Wta, bta, Wtb, btb, nsc, out);
}

// Round 3
// 552.822 us; speedup vs baseline: 1.3118x; 1.3118x over previous
//
#include <hip/hip_runtime.h>
#include <math.h>

typedef __attribute__((ext_vector_type(8))) short short8;
typedef __attribute__((ext_vector_type(4))) float f32x4;

#define B_ 16
#define T_ 256
#define I_ 64
#define H_ 128
#define K_ 64
#define U_ 256
#define KC 16
#define NTHR 512

#define OUT_OFF_P (B_*T_*H_)              /* 524288 */
#define OUT_OFF_LW (OUT_OFF_P + B_*K_*H_) /* 655360 */

__device__ __forceinline__ unsigned short f2bf(float x) {
    unsigned int u = __float_as_uint(x);
    u += 0x7fffu + ((u >> 16) & 1u);   // RNE for finite inputs
    return (unsigned short)(u >> 16);
}
__device__ __forceinline__ float fast_tanh(float x) {
    float e = __expf(2.0f * x);
    return 1.0f - 2.0f * __builtin_amdgcn_rcpf(e + 1.0f);
}
__device__ __forceinline__ float fast_sigmoid(float x) {
    return __builtin_amdgcn_rcpf(1.0f + __expf(-x));
}
// XOR-swizzle: breaks the 256B/512B row-stride bank collision on ds_read_b128
__device__ __forceinline__ unsigned int swz_p(unsigned int row, unsigned int col) { // [16][128] bf16
    unsigned int byte = row * 256u + col * 2u;
    byte ^= (row & 7u) << 4;
    return byte >> 1;
}
__device__ __forceinline__ unsigned int swz_b(unsigned int row, unsigned int col) { // [16][256] bf16
    unsigned int byte = row * 512u + col * 2u;
    byte ^= (row & 7u) << 4;
    return byte >> 1;
}

// raw barrier: LDS-visibility only; vmem (eps prefetch, atomics) stays in flight
#define BAR() do { asm volatile("s_waitcnt lgkmcnt(0)" ::: "memory"); \
                   __builtin_amdgcn_s_barrier(); \
                   __builtin_amdgcn_sched_barrier(0); } while (0)

#define MFMA16(a, bfrag, c) __builtin_amdgcn_mfma_f32_16x16x32_bf16((a), (bfrag), (c), 0, 0, 0)

__global__ __launch_bounds__(NTHR, 2) void pf_kernel(
    const float* __restrict__ x, const float* __restrict__ tspan,
    const float* __restrict__ eps, const float* __restrict__ Wb,
    const float* __restrict__ bb,
    const float* __restrict__ Wf1, const float* __restrict__ bf1,
    const float* __restrict__ Wf2, const float* __restrict__ bf2,
    const float* __restrict__ Wta, const float* __restrict__ bta,
    const float* __restrict__ Wtb, const float* __restrict__ btb,
    const float* __restrict__ nscale, float* __restrict__ out)
{
    const int tid  = threadIdx.x;
    const int lane = tid & 63;
    const int wv   = tid >> 6;        // wave 0..7
    const int ln15 = lane & 15;
    const int l4   = lane >> 4;
    const int bid  = blockIdx.x;      // 0..63
    const int b    = bid >> 2;
    const int k0   = (bid & 3) * KC;

    __shared__ unsigned short p_bf[KC * H_];     // particles bf16, swizzled (4KB)
    __shared__ unsigned short bbk_bf[KC * U_];   // backbone acts bf16, swizzled (8KB)
    __shared__ unsigned short x_bf[T_ * I_];     // whole x[b] pre-converted (32KB)
    __shared__ float ts_lds[T_];                 // (1KB)

    for (int i = tid; i < KC * H_; i += NTHR) p_bf[i] = 0;
    for (int i = tid; i < T_ * I_; i += NTHR) x_bf[i] = f2bf(x[b * (T_ * I_) + i]);
    for (int i = tid; i < T_; i += NTHR) ts_lds[i] = tspan[b * T_ + i];

    // ---- GEMM1 weights: wave owns bbk cols [wv*32, wv*32+32) ----
    short8 B1[6][2];
    #pragma unroll
    for (int kt = 0; kt < 6; ++kt) {
        #pragma unroll
        for (int ct = 0; ct < 2; ++ct) {
            short8 f;
            const int col = wv * 32 + ct * 16 + ln15;
            #pragma unroll
            for (int j = 0; j < 8; ++j) f[j] = (short)f2bf(Wb[(kt * 32 + l4 * 8 + j) * U_ + col]);
            B1[kt][ct] = f;
        }
    }
    float bias1[2];
    #pragma unroll
    for (int ct = 0; ct < 2; ++ct) bias1[ct] = bb[wv * 32 + ct * 16 + ln15];

    // ---- GEMM2 weights: wave owns h cols [wv*16, wv*16+16) for ALL 4 heads ----
    const float* Whp[4] = {Wf1, Wf2, Wta, Wtb};
    const int hc = wv * 16 + ln15;
    short8 B2[4][8];
    #pragma unroll
    for (int hd = 0; hd < 4; ++hd) {
        #pragma unroll
        for (int kt = 0; kt < 8; ++kt) {
            short8 f;
            #pragma unroll
            for (int j = 0; j < 8; ++j) f[j] = (short)f2bf(Whp[hd][(kt * 32 + l4 * 8 + j) * H_ + hc]);
            B2[hd][kt] = f;
        }
    }
    const float bf1c = bf1[hc], bf2c = bf2[hc];
    const float btac = bta[hc], btbc = btb[hc];
    const float nscc = nscale[hc];

    // pin fragments so the compiler can't rematerialize/sink the loads into the loop
    #pragma unroll
    for (int kt = 0; kt < 6; ++kt) asm volatile("" : "+v"(B1[kt][0]), "+v"(B1[kt][1]));
    #pragma unroll
    for (int hd = 0; hd < 4; ++hd) {
        #pragma unroll
        for (int kt = 0; kt < 8; ++kt) asm volatile("" : "+v"(B2[hd][kt]));
    }

    if ((bid & 3) == 0 && tid < K_)
        out[OUT_OFF_LW + b * K_ + tid] = -4.1588830833596715f; // -log(64)

    __syncthreads();   // full drain once: prologue LDS + global

    // eps lane base: ((t*B + b)*K + k0 + l4*4 + r)*H + hc
    const float* ep0 = eps + ((size_t)(b * K_ + k0 + l4 * 4)) * H_ + hc;
    float ecur[4];
    #pragma unroll
    for (int r = 0; r < 4; ++r) ecur[r] = ep0[r * H_];
    float tscur = ts_lds[0];

    const f32x4 zero4 = {0.f, 0.f, 0.f, 0.f};

    for (int t = 0; t < T_; ++t) {
        // ---- prefetch next-step inputs (consumed next iteration; never drained at barriers) ----
        const int tn = (t + 1 < T_) ? t + 1 : t;
        const float* epn = ep0 + (size_t)tn * (B_ * K_ * H_);
        float enext[4];
        #pragma unroll
        for (int r = 0; r < 4; ++r) enext[r] = epn[r * H_];
        const float tsn = ts_lds[tn];

        // ---- phase 1: GEMM1  z(16x192) @ Wb -> bbk(16x256) ----
        f32x4 acc0 = zero4, acc1 = zero4;
        const short8 ax0 = *(const short8*)&x_bf[t * I_ + l4 * 8];        // broadcast reads
        const short8 ax1 = *(const short8*)&x_bf[t * I_ + 32 + l4 * 8];
        acc0 = MFMA16(ax0, B1[0][0], acc0); acc1 = MFMA16(ax0, B1[0][1], acc1);
        acc0 = MFMA16(ax1, B1[1][0], acc0); acc1 = MFMA16(ax1, B1[1][1], acc1);
        #pragma unroll
        for (int kt = 0; kt < 4; ++kt) {
            const short8 ap = *(const short8*)&p_bf[swz_p(ln15, kt * 32 + l4 * 8)];
            acc0 = MFMA16(ap, B1[2 + kt][0], acc0);
            acc1 = MFMA16(ap, B1[2 + kt][1], acc1);
        }
        #pragma unroll
        for (int r = 0; r < 4; ++r) {
            const int row = l4 * 4 + r;
            bbk_bf[swz_b(row, wv * 32 + ln15)]      = f2bf(1.7159f * fast_tanh(0.666f * (acc0[r] + bias1[0])));
            bbk_bf[swz_b(row, wv * 32 + 16 + ln15)] = f2bf(1.7159f * fast_tanh(0.666f * (acc1[r] + bias1[1])));
        }
        BAR();

        // ---- phase 2: GEMM2 (all 4 heads, own 16 h-cols) + in-register combine ----
        f32x4 a_f1 = zero4, a_f2 = zero4, a_ta = zero4, a_tb = zero4;
        #pragma unroll
        for (int kt = 0; kt < 8; ++kt) {
            const short8 a = *(const short8*)&bbk_bf[swz_b(ln15, kt * 32 + l4 * 8)];
            a_f1 = MFMA16(a, B2[0][kt], a_f1);
            a_f2 = MFMA16(a, B2[1][kt], a_f2);
            a_ta = MFMA16(a, B2[2][kt], a_ta);
            a_tb = MFMA16(a, B2[3][kt], a_tb);
        }
        const float sq = sqrtf(tscur);
        float psum = 0.f;
        #pragma unroll
        for (int r = 0; r < 4; ++r) {
            const int row = l4 * 4 + r;
            const float f1v = fast_tanh(a_f1[r] + bf1c);
            const float f2v = fast_tanh(a_f2[r] + bf2c);
            const float tiv = fast_sigmoid((a_ta[r] + btac) * tscur + (a_tb[r] + btbc));
            const float np  = f1v + tiv * (f2v - f1v) + nscc * sq * ecur[r];
            p_bf[swz_p(row, hc)] = f2bf(np);
            psum += np;
            if (t == T_ - 1)
                out[OUT_OFF_P + (size_t)(b * K_ + k0 + row) * H_ + hc] = np;
        }
        // block-wide mean over 16 rows: in-lane (4 rows) done; sum over l4 groups
        psum += __shfl_xor(psum, 16);
        psum += __shfl_xor(psum, 32);
        if (lane < 16)
            atomicAdd(&out[(size_t)(b * T_ + t) * H_ + wv * 16 + lane], psum * (1.0f / 64.0f));

        #pragma unroll
        for (int r = 0; r < 4; ++r) ecur[r] = enext[r];
        tscur = tsn;
        BAR();
    }
}

extern "C" void kernel_launch(void* const* d_in, const int* in_sizes, int n_in,
                              void* d_out, int out_size, void* d_ws, size_t ws_size,
                              hipStream_t stream) {
    const float* x    = (const float*)d_in[0];
    const float* tsp  = (const float*)d_in[1];
    const float* eps  = (const float*)d_in[2];
    const float* Wb   = (const float*)d_in[3];
    const float* bb   = (const float*)d_in[4];
    const float* Wf1  = (const float*)d_in[5];
    const float* bf1  = (const float*)d_in[6];
    const float* Wf2  = (const float*)d_in[7];
    const float* bf2  = (const float*)d_in[8];
    const float* Wta  = (const float*)d_in[9];
    const float* bta  = (const float*)d_in[10];
    const float* Wtb  = (const float*)d_in[11];
    const float* btb  = (const float*)d_in[12];
    const float* nsc  = (const float*)d_in[13];
    float* out = (float*)d_out;

    // outputs region is accumulated with atomics -> zero every launch
    (void)hipMemsetAsync(d_out, 0, (size_t)OUT_OFF_P * sizeof(float), stream);
    pf_kernel<<<dim3(64), dim3(NTHR), 0, stream>>>(
        x, tsp, eps, Wb, bb, Wf1, bf1, Wf2, bf2, Wta, bta, Wtb, btb, nsc, out);
}